// Round 10
// baseline (88.201 us; speedup 1.0000x reference)
//
#include <hip/hip_runtime.h>
#include <hip/hip_bf16.h>

namespace {

using frag_t    = __attribute__((ext_vector_type(8))) short;   // 8 bf16 = 16 B
using f32x4     = __attribute__((ext_vector_type(4))) float;   // MFMA acc
using float4_t  = __attribute__((ext_vector_type(4))) float;

constexpr int BATCH = 32;
constexpr int CIN   = 64;
constexpr int HWD   = 56;
constexpr int KOUT  = 128;
constexpr int SP    = HWD * HWD;        // 3136 = 49*64
constexpr int KD    = 9 * CIN;          // 576
constexpr int BN    = 64;               // spatial tile per block
constexpr int PADR  = 64;               // pad rows per image edge (masked garbage)
constexpr int XTR   = SP + 2 * PADR;    // 3264 rows per padded image
constexpr int NTILES= SP / BN;          // 49
constexpr int NWG   = NTILES * BATCH;   // 1568 = 8 * 196
constexpr int TT    = BATCH * (SP / 64);
constexpr int WB    = (KOUT * KD + 255) / 256;

__device__ inline unsigned short f2bf(float f) {
    __hip_bfloat16 h = __float2bfloat16(f);
    return __builtin_bit_cast(unsigned short, h);
}

// ---- prep: (a) transpose x -> xT[b][PADR+sp][c] bf16 (padded); (b) w -> wpA ----
__global__ __launch_bounds__(256)
void prep_kernel(const float* __restrict__ x, const float* __restrict__ w,
                 unsigned short* __restrict__ wpA, unsigned short* __restrict__ xT)
{
    if (blockIdx.x >= TT) {
        const int idx = (blockIdx.x - TT) * 256 + threadIdx.x;
        if (idx < KOUT * KD) {
            const int kout = idx / KD, kk = idx - kout * KD;
            const int kc = kk >> 5, e = kk & 31;
            const int t = kk >> 6, c = kk & 63;
            const int ky = t / 3, kx = t - ky * 3;
            wpA[(kc * KOUT + kout) * 32 + e] = f2bf(w[((kout * CIN + c) * 3 + ky) * 3 + kx]);
        }
        return;
    }
    __shared__ float ls[64][68];
    const int bb   = blockIdx.x / (SP / 64);
    const int tile = blockIdx.x - bb * (SP / 64);
    const int sp0  = tile * 64;
    const int tid  = threadIdx.x;
    const int cq   = tid >> 4;
    const int spo  = (tid & 15) * 4;
    const float* xb = x + (size_t)bb * CIN * SP;
    #pragma unroll
    for (int j = 0; j < 4; ++j) {
        const int c = cq + 16 * j;
        float4_t v = *(const float4_t*)&xb[(size_t)c * SP + sp0 + spo];
        ls[spo + 0][c] = v.x; ls[spo + 1][c] = v.y;
        ls[spo + 2][c] = v.z; ls[spo + 3][c] = v.w;
    }
    __syncthreads();
    unsigned short* xo = xT + ((size_t)bb * XTR + PADR + sp0) * 64;
    #pragma unroll
    for (int j = 0; j < 2; ++j) {
        const int s  = tid + 256 * j;
        const int sp = s >> 3, e = s & 7;
        frag_t u;
        #pragma unroll
        for (int q = 0; q < 8; ++q)
            u[q] = (short)f2bf(ls[sp][e * 8 + q]);
        *(frag_t*)&xo[sp * 64 + e * 8] = u;
    }
}

// ---- direct implicit-GEMM conv: no LDS, no barriers; B straight from L2/L3 ----
__global__ __launch_bounds__(256, 4)
void conv_direct(const unsigned short* __restrict__ xT, const unsigned short* __restrict__ wpA,
                 const float* __restrict__ off, float* __restrict__ out)
{
    const int d    = blockIdx.x;
    const int wk   = (d & 7) * (NWG / 8) + (d >> 3);   // bijective XCD swizzle
    const int b    = wk / NTILES;
    const int sp0  = (wk - b * NTILES) * BN;
    const int lane = threadIdx.x & 63;
    const int wid  = threadIdx.x >> 6;

    const int wm  = wid * 32;          // 32 kouts per wave
    const int l15 = lane & 15;
    const int l4  = lane >> 4;

    // ---------- per-(tap, nf) validity masks (bit t*4+nf) ----------
    unsigned long long mbits = 0ull;
    int yv[4], xv[4];
    #pragma unroll
    for (int nf = 0; nf < 4; ++nf) {
        const int sp = sp0 + nf * 16 + l15;
        yv[nf] = sp / HWD;
        xv[nf] = sp - yv[nf] * HWD;
    }
    #pragma unroll
    for (int t = 0; t < 9; ++t) {
        const int dy = t / 3 - 1, dx = t % 3 - 1;
        #pragma unroll
        for (int nf = 0; nf < 4; ++nf) {
            const bool v = ((unsigned)(yv[nf] + dy) < (unsigned)HWD) &
                           ((unsigned)(xv[nf] + dx) < (unsigned)HWD);
            mbits |= (unsigned long long)(v ? 1 : 0) << (t * 4 + nf);
        }
    }

    const unsigned short* abase = wpA + (size_t)(wm + l15) * 32 + 8 * l4;
    // per-lane B base: padded row (PADR + sp0 + l15), channel 8*l4
    const unsigned short* bbase = xT + ((size_t)b * XTR + PADR + sp0 + l15) * 64 + 8 * l4;
    const frag_t zf = {0,0,0,0,0,0,0,0};

    f32x4 acc[2][4] = {};              // [mi][nf]

    // ---------- K loop: 18 chunks, fully unrolled, loads straight from global ----------
    #pragma unroll
    for (int kc = 0; kc < 18; ++kc) {
        const int t     = kc >> 1;
        const int ch    = kc & 1;
        const int shift = (t / 3 - 1) * HWD + (t % 3 - 1);
        frag_t a[2], bfr[4];
        a[0] = *(const frag_t*)(abase + (size_t)kc * KOUT * 32);
        a[1] = *(const frag_t*)(abase + (size_t)kc * KOUT * 32 + 16 * 32);
        const unsigned m4 = (unsigned)((mbits >> (t * 4)) & 15ull);
        #pragma unroll
        for (int nf = 0; nf < 4; ++nf) {
            const frag_t bl = *(const frag_t*)(bbase
                                + (ptrdiff_t)(shift + 16 * nf) * 64 + ch * 32);
            bfr[nf] = ((m4 >> nf) & 1u) ? bl : zf;
        }
        #pragma unroll
        for (int mi = 0; mi < 2; ++mi)
            #pragma unroll
            for (int nf = 0; nf < 4; ++nf)
                acc[mi][nf] = __builtin_amdgcn_mfma_f32_16x16x32_bf16(
                    a[mi], bfr[nf], acc[mi][nf], 0, 0, 0);
    }

    // ---------- epilogue (tiles divide SP exactly: no guards) ----------
    const int spn = sp0 + l15;
    #pragma unroll
    for (int mi = 0; mi < 2; ++mi) {
        const int km = wm + 16 * mi + 4 * l4;
        #pragma unroll
        for (int reg = 0; reg < 4; ++reg) {
            const int  kk  = km + reg;
            const float ofv = off[kk];
            float* ob = out + (size_t)(b * KOUT + kk) * SP;
            #pragma unroll
            for (int nf = 0; nf < 4; ++nf)
                ob[spn + 16 * nf] = acc[mi][nf][reg] + ofv;
        }
    }
}

// ---- fallback: round-1 fp32 direct conv ----
__global__ __launch_bounds__(256)
void conv3x3_kernel(const float* __restrict__ x, const float* __restrict__ w,
                    const float* __restrict__ off, float* __restrict__ out)
{
    const int s  = blockIdx.x * 256 + threadIdx.x;
    const int b  = s / SP;
    const int sp = s - b * SP;
    const int y  = sp / HWD;
    const int xx = sp - y * HWD;
    const int k0 = blockIdx.y * 4;

    const int   xm1 = (xx > 0) ? xx - 1 : 0;
    const int   xp1 = (xx < HWD - 1) ? xx + 1 : HWD - 1;
    const float m0  = (xx > 0) ? 1.f : 0.f;
    const float m2  = (xx < HWD - 1) ? 1.f : 0.f;

    int ro[3]; float msk[3][3];
    #pragma unroll
    for (int ky = 0; ky < 3; ++ky) {
        const int  yy = y + ky - 1;
        const bool ok = (unsigned)yy < (unsigned)HWD;
        const float rm = ok ? 1.f : 0.f;
        ro[ky] = (ok ? yy : 0) * HWD;
        msk[ky][0] = rm * m0; msk[ky][1] = rm; msk[ky][2] = rm * m2;
    }
    float acc[4] = {0.f, 0.f, 0.f, 0.f};
    const float* xb = x + (size_t)b * CIN * SP;
    for (int c = 0; c < CIN; ++c) {
        const float* xc = xb + (size_t)c * SP;
        #pragma unroll
        for (int ky = 0; ky < 3; ++ky) {
            const float* xr = xc + ro[ky];
            const float v0 = xr[xm1] * msk[ky][0];
            const float v1 = xr[xx]  * msk[ky][1];
            const float v2 = xr[xp1] * msk[ky][2];
            const int wi = c * 9 + ky * 3;
            #pragma unroll
            for (int kk = 0; kk < 4; ++kk) {
                const float* wr = w + (size_t)(k0 + kk) * (CIN * 9) + wi;
                acc[kk] = fmaf(v0, wr[0], acc[kk]);
                acc[kk] = fmaf(v1, wr[1], acc[kk]);
                acc[kk] = fmaf(v2, wr[2], acc[kk]);
            }
        }
    }
    #pragma unroll
    for (int kk = 0; kk < 4; ++kk)
        out[(size_t)(b * KOUT + k0 + kk) * SP + sp] = acc[kk] + off[k0 + kk];
}

} // namespace

extern "C" void kernel_launch(void* const* d_in, const int* in_sizes, int n_in,
                              void* d_out, int out_size, void* d_ws, size_t ws_size,
                              hipStream_t stream)
{
    const float* x   = (const float*)d_in[0];
    const float* w   = (const float*)d_in[1];
    const float* off = (const float*)d_in[2];
    float* out = (float*)d_out;

    const size_t wpa_bytes = (size_t)KOUT * KD * 2;              // 147456
    const size_t xt_bytes  = (size_t)BATCH * XTR * CIN * 2;      // 13369344 (padded)

    if (ws_size >= wpa_bytes + xt_bytes) {
        unsigned short* wpA = (unsigned short*)d_ws;
        unsigned short* xT  = (unsigned short*)((char*)d_ws + wpa_bytes);
        prep_kernel<<<TT + WB, 256, 0, stream>>>(x, w, wpA, xT);
        conv_direct<<<NWG, dim3(256, 1, 1), 0, stream>>>(xT, wpA, off, out);
    } else {
        dim3 grid((BATCH * SP) / 256, KOUT / 4);
        conv3x3_kernel<<<grid, dim3(256, 1, 1), 0, stream>>>(x, w, off, out);
    }
}

// Round 11
// 66.486 us; speedup vs baseline: 1.3266x; 1.3266x over previous
//
#include <hip/hip_runtime.h>
#include <hip/hip_bf16.h>

namespace {

using frag_t    = __attribute__((ext_vector_type(8))) short;   // 8 bf16 = 16 B
using f32x4     = __attribute__((ext_vector_type(4))) float;   // MFMA acc
using float4_t  = __attribute__((ext_vector_type(4))) float;

constexpr int BATCH = 32;
constexpr int CIN   = 64;
constexpr int HWD   = 56;
constexpr int KOUT  = 128;
constexpr int SP    = HWD * HWD;        // 3136
constexpr int KD    = 9 * CIN;          // 576
constexpr int BN    = 256;              // spatial tile per iteration
constexpr int HALO  = 57;
constexpr int WIN   = BN + 2 * HALO;    // 370 staged rows (46.25 KB)
constexpr int T13   = 13;               // 256-sp tiles per image (last partial)
constexpr int NSLOT = T13 * BATCH;      // 416 sp-tile slots
constexpr int NBLK  = 256;              // 1 block/CU; d>>7 = kh, d&127 = pair
constexpr int TT    = BATCH * (SP / 64);            // 1568 transpose blocks
constexpr int WB2   = (KOUT * KD) / 256;            // 288 weight-repack blocks
constexpr int AHALF = 18 * 4 * 64 * 8;              // 36864 ushorts per kh half

__device__ inline unsigned short f2bf(float f) {
    __hip_bfloat16 h = __float2bfloat16(f);
    return __builtin_bit_cast(unsigned short, h);
}

// ---- prep: (a) transpose x -> xT[b][sp][c] bf16; (b) repack w lane-ordered ----
// wpA2[kh][kc][mi][lane][8]: lane l = l15 + 16*l4 reads kout=kh*64+mi*16+l15,
// k-elems kk = kc*32 + l4*8 + q  ->  A-frag ds_read is 1KB contiguous in lane order.
__global__ __launch_bounds__(256)
void prep_kernel(const float* __restrict__ x, const float* __restrict__ w,
                 unsigned short* __restrict__ wpA2, unsigned short* __restrict__ xT)
{
    if (blockIdx.x >= TT) {
        const int idx = (blockIdx.x - TT) * 256 + threadIdx.x;   // < 73728
        const int q   = idx & 7;
        int r1 = idx >> 3;
        const int l  = r1 & 63;  r1 >>= 6;
        const int mi = r1 & 3;   r1 >>= 2;
        const int kc = r1 % 18;
        const int kh = r1 / 18;
        const int kout = kh * 64 + mi * 16 + (l & 15);
        const int kk   = kc * 32 + (l >> 4) * 8 + q;
        const int c = kk & 63, t = kk >> 6, ky = t / 3, kx = t - ky * 3;
        wpA2[idx] = f2bf(w[((kout * CIN + c) * 3 + ky) * 3 + kx]);
        return;
    }
    __shared__ float ls[64][68];
    const int bb   = blockIdx.x / (SP / 64);
    const int tile = blockIdx.x - bb * (SP / 64);
    const int sp0  = tile * 64;
    const int tid  = threadIdx.x;
    const int cq   = tid >> 4;
    const int spo  = (tid & 15) * 4;
    const float* xb = x + (size_t)bb * CIN * SP;
    #pragma unroll
    for (int j = 0; j < 4; ++j) {
        const int c = cq + 16 * j;
        float4_t v = *(const float4_t*)&xb[(size_t)c * SP + sp0 + spo];
        ls[spo + 0][c] = v.x; ls[spo + 1][c] = v.y;
        ls[spo + 2][c] = v.z; ls[spo + 3][c] = v.w;
    }
    __syncthreads();
    unsigned short* xo = xT + (size_t)(bb * SP + sp0) * 64;
    #pragma unroll
    for (int j = 0; j < 2; ++j) {
        const int s  = tid + 256 * j;
        const int sp = s >> 3, e = s & 7;
        frag_t u;
        #pragma unroll
        for (int q = 0; q < 8; ++q)
            u[q] = (short)f2bf(ls[sp][e * 8 + q]);
        *(frag_t*)&xo[sp * 64 + e * 8] = u;
    }
}

// ---- K=576 GEMM conv: A staged once per block in LDS; pure LDS+MFMA K-loop ----
__global__ __launch_bounds__(256)
void conv_gemm(const unsigned short* __restrict__ xT, const unsigned short* __restrict__ wpA2,
               const float* __restrict__ off, float* __restrict__ out)
{
    __shared__ unsigned short As[AHALF];      // 72 KB: this block's 64-kout A half
    __shared__ unsigned short xs[WIN * 64];   // 46.25 KB, swizzled (r&7)<<3 XOR

    const int d    = blockIdx.x;
    const int kh   = d >> 7;                  // kout half
    const int pair = d & 127;                 // d and d+128 share xs windows (same XCD)
    const int tid  = threadIdx.x;
    const int lane = tid & 63;
    const int wid  = tid >> 6;

    // ---------- stage A once: 73728 B contiguous, linear LDS ----------
    {
        const unsigned short* src = wpA2 + kh * AHALF + tid * 8;
        #pragma unroll
        for (int it = 0; it < 18; ++it) {
            __builtin_amdgcn_global_load_lds(
                (const __attribute__((address_space(1))) unsigned int*)(src + it * 2048),
                (__attribute__((address_space(3))) unsigned int*)&As[it * 2048 + tid * 8],
                16, 0, 0);
        }
    }

    const int wn  = wid * 64;          // wave's spatial offset in tile
    const int l15 = lane & 15;
    const int l4  = lane >> 4;
    const int cread = 8 * l4;
    const int lsw = ((lane & 7) * 8) ^ ((lane >> 3) << 3);
    const frag_t zf = {0,0,0,0,0,0,0,0};

    for (int i = 0; i < 4; ++i) {
        const int s = pair + i * 128;
        if (s >= NSLOT) break;
        const int img = s / T13;
        const int sp0 = (s - img * T13) * BN;

        // ---------- stage xs window (47 KB): pre-swizzled src, direct to LDS ----------
        {
            const unsigned short* xb = xT + (size_t)img * SP * 64;
            #pragma unroll
            for (int it = 0; it < 12; ++it) {
                const int R0 = it * 32 + wid * 8;
                const int r  = R0 + (lane >> 3);
                if (r < WIN) {
                    int g = sp0 - HALO + r;
                    g = min(max(g, 0), SP - 1);
                    __builtin_amdgcn_global_load_lds(
                        (const __attribute__((address_space(1))) unsigned int*)
                            (xb + (size_t)g * 64 + lsw),
                        (__attribute__((address_space(3))) unsigned int*)
                            &xs[R0 * 64 + lane * 8],
                        16, 0, 0);
                }
            }
        }
        asm volatile("s_waitcnt vmcnt(0)" ::: "memory");
        __syncthreads();   // iter 0 also covers the A stage

        // ---------- per-(tap, nf) validity masks ----------
        unsigned long long mbits = 0ull;
        int yv[4], xv[4];
        #pragma unroll
        for (int nf = 0; nf < 4; ++nf) {
            const int sp = sp0 + wn + nf * 16 + l15;
            yv[nf] = sp / HWD;
            xv[nf] = sp - yv[nf] * HWD;
        }
        #pragma unroll
        for (int t = 0; t < 9; ++t) {
            const int dy = t / 3 - 1, dx = t % 3 - 1;
            #pragma unroll
            for (int nf = 0; nf < 4; ++nf) {
                const bool v = ((unsigned)(yv[nf] + dy) < (unsigned)HWD) &
                               ((unsigned)(xv[nf] + dx) < (unsigned)HWD);
                mbits |= (unsigned long long)(v ? 1 : 0) << (t * 4 + nf);
            }
        }

        // ---------- K loop: pure LDS + MFMA ----------
        f32x4 acc[4][4] = {};          // [mi][nf]
        #pragma unroll
        for (int kc = 0; kc < 18; ++kc) {
            const int t  = kc >> 1;
            const int c0 = (kc & 1) * 32;
            const int shift = (t / 3 - 1) * HWD + (t % 3 - 1);
            const int row0  = wn + l15 + HALO + shift;     // in [0, 369]
            const int sw    = (row0 & 7) << 3;
            frag_t a[4], bfr[4];
            #pragma unroll
            for (int mi = 0; mi < 4; ++mi)
                a[mi] = *(const frag_t*)&As[(kc * 4 + mi) * 512 + lane * 8];
            const unsigned m4 = (unsigned)((mbits >> (t * 4)) & 15ull);
            #pragma unroll
            for (int nf = 0; nf < 4; ++nf) {
                const frag_t bl = *(const frag_t*)&xs[(row0 + 16 * nf) * 64
                                                     + ((c0 + cread) ^ sw)];
                bfr[nf] = ((m4 >> nf) & 1u) ? bl : zf;
            }
            #pragma unroll
            for (int mi = 0; mi < 4; ++mi)
                #pragma unroll
                for (int nf = 0; nf < 4; ++nf)
                    acc[mi][nf] = __builtin_amdgcn_mfma_f32_16x16x32_bf16(
                        a[mi], bfr[nf], acc[mi][nf], 0, 0, 0);
        }

        // ---------- guarded stores (tail tile / OOB waves skip) ----------
        const int spn = sp0 + wn + l15;
        #pragma unroll
        for (int mi = 0; mi < 4; ++mi) {
            const int km = kh * 64 + mi * 16 + 4 * l4;
            #pragma unroll
            for (int reg = 0; reg < 4; ++reg) {
                const int  kk  = km + reg;
                const float ofv = off[kk];
                float* ob = out + (size_t)(img * KOUT + kk) * SP;
                #pragma unroll
                for (int nf = 0; nf < 4; ++nf) {
                    const int sp = spn + 16 * nf;
                    if (sp < SP) ob[sp] = acc[mi][nf][reg] + ofv;
                }
            }
        }
        __syncthreads();   // protect xs before next iteration's overwrite
    }
}

// ---- fallback: round-1 fp32 direct conv ----
__global__ __launch_bounds__(256)
void conv3x3_kernel(const float* __restrict__ x, const float* __restrict__ w,
                    const float* __restrict__ off, float* __restrict__ out)
{
    const int s  = blockIdx.x * 256 + threadIdx.x;
    const int b  = s / SP;
    const int sp = s - b * SP;
    const int y  = sp / HWD;
    const int xx = sp - y * HWD;
    const int k0 = blockIdx.y * 4;

    const int   xm1 = (xx > 0) ? xx - 1 : 0;
    const int   xp1 = (xx < HWD - 1) ? xx + 1 : HWD - 1;
    const float m0  = (xx > 0) ? 1.f : 0.f;
    const float m2  = (xx < HWD - 1) ? 1.f : 0.f;

    int ro[3]; float msk[3][3];
    #pragma unroll
    for (int ky = 0; ky < 3; ++ky) {
        const int  yy = y + ky - 1;
        const bool ok = (unsigned)yy < (unsigned)HWD;
        const float rm = ok ? 1.f : 0.f;
        ro[ky] = (ok ? yy : 0) * HWD;
        msk[ky][0] = rm * m0; msk[ky][1] = rm; msk[ky][2] = rm * m2;
    }
    float acc[4] = {0.f, 0.f, 0.f, 0.f};
    const float* xb = x + (size_t)b * CIN * SP;
    for (int c = 0; c < CIN; ++c) {
        const float* xc = xb + (size_t)c * SP;
        #pragma unroll
        for (int ky = 0; ky < 3; ++ky) {
            const float* xr = xc + ro[ky];
            const float v0 = xr[xm1] * msk[ky][0];
            const float v1 = xr[xx]  * msk[ky][1];
            const float v2 = xr[xp1] * msk[ky][2];
            const int wi = c * 9 + ky * 3;
            #pragma unroll
            for (int kk = 0; kk < 4; ++kk) {
                const float* wr = w + (size_t)(k0 + kk) * (CIN * 9) + wi;
                acc[kk] = fmaf(v0, wr[0], acc[kk]);
                acc[kk] = fmaf(v1, wr[1], acc[kk]);
                acc[kk] = fmaf(v2, wr[2], acc[kk]);
            }
        }
    }
    #pragma unroll
    for (int kk = 0; kk < 4; ++kk)
        out[(size_t)(b * KOUT + k0 + kk) * SP + sp] = acc[kk] + off[k0 + kk];
}

} // namespace

extern "C" void kernel_launch(void* const* d_in, const int* in_sizes, int n_in,
                              void* d_out, int out_size, void* d_ws, size_t ws_size,
                              hipStream_t stream)
{
    const float* x   = (const float*)d_in[0];
    const float* w   = (const float*)d_in[1];
    const float* off = (const float*)d_in[2];
    float* out = (float*)d_out;

    const size_t wpa_bytes = (size_t)KOUT * KD * 2;          // 147456
    const size_t xt_bytes  = (size_t)BATCH * SP * CIN * 2;   // 12845056

    if (ws_size >= wpa_bytes + xt_bytes) {
        unsigned short* wpA2 = (unsigned short*)d_ws;
        unsigned short* xT   = (unsigned short*)((char*)d_ws + wpa_bytes);
        prep_kernel<<<TT + WB2, 256, 0, stream>>>(x, w, wpA2, xT);
        conv_gemm<<<NBLK, dim3(256, 1, 1), 0, stream>>>(xT, wpA2, off, out);
    } else {
        dim3 grid((BATCH * SP) / 256, KOUT / 4);
        conv3x3_kernel<<<grid, dim3(256, 1, 1), 0, stream>>>(x, w, off, out);
    }
}

// Round 12
// 53.933 us; speedup vs baseline: 1.6354x; 1.2328x over previous
//
#include <hip/hip_runtime.h>
#include <hip/hip_bf16.h>

namespace {

using frag_t    = __attribute__((ext_vector_type(8))) short;   // 8 bf16 = 16 B
using f32x4     = __attribute__((ext_vector_type(4))) float;   // MFMA acc
using float4_t  = __attribute__((ext_vector_type(4))) float;

constexpr int BATCH = 32;
constexpr int CIN   = 64;
constexpr int HWD   = 56;
constexpr int KOUT  = 128;
constexpr int SP    = HWD * HWD;        // 3136
constexpr int KD    = 9 * CIN;          // 576
constexpr int BN    = 128;              // spatial tile
constexpr int HALO  = 57;
constexpr int WINR  = BN + 2 * HALO;    // 242 staged rows (31 KB)
constexpr int NT    = SP / BN + 1;      // 25 tiles/image (last half)
constexpr int NWG   = NT * BATCH;       // 800 = 8 * 100
constexpr int TT    = BATCH * (SP / 64);            // 1568 transpose blocks
constexpr int WB2   = (KOUT * KD) / 256;            // 288 weight blocks
constexpr int KHSTR = 18 * 2048;                    // wpA2 kh stride (36864)

__device__ inline unsigned short f2bf(float f) {
    __hip_bfloat16 h = __float2bfloat16(f);
    return __builtin_bit_cast(unsigned short, h);
}

// ---- prep: (a) transpose x -> xT[b][sp][c] bf16; (b) repack w lane-ordered ----
// wpA2[kh][kc][mi][lane][8]: lane l: kout = kh*64 + mi*16 + (l&15),
// kk = kc*32 + (l>>4)*8 + q  -> A-frag ds_read 1KB contiguous. (R11-verified)
__global__ __launch_bounds__(256)
void prep_kernel(const float* __restrict__ x, const float* __restrict__ w,
                 unsigned short* __restrict__ wpA2, unsigned short* __restrict__ xT)
{
    if (blockIdx.x >= TT) {
        const int idx = (blockIdx.x - TT) * 256 + threadIdx.x;   // < 73728
        const int q   = idx & 7;
        int r1 = idx >> 3;
        const int l  = r1 & 63;  r1 >>= 6;
        const int mi = r1 & 3;   r1 >>= 2;
        const int kc = r1 % 18;
        const int kh = r1 / 18;
        const int kout = kh * 64 + mi * 16 + (l & 15);
        const int kk   = kc * 32 + (l >> 4) * 8 + q;
        const int c = kk & 63, t = kk >> 6, ky = t / 3, kx = t - ky * 3;
        wpA2[idx] = f2bf(w[((kout * CIN + c) * 3 + ky) * 3 + kx]);
        return;
    }
    __shared__ float ls[64][68];
    const int bb   = blockIdx.x / (SP / 64);
    const int tile = blockIdx.x - bb * (SP / 64);
    const int sp0  = tile * 64;
    const int tid  = threadIdx.x;
    const int cq   = tid >> 4;
    const int spo  = (tid & 15) * 4;
    const float* xb = x + (size_t)bb * CIN * SP;
    #pragma unroll
    for (int j = 0; j < 4; ++j) {
        const int c = cq + 16 * j;
        float4_t v = *(const float4_t*)&xb[(size_t)c * SP + sp0 + spo];
        ls[spo + 0][c] = v.x; ls[spo + 1][c] = v.y;
        ls[spo + 2][c] = v.z; ls[spo + 3][c] = v.w;
    }
    __syncthreads();
    unsigned short* xo = xT + (size_t)(bb * SP + sp0) * 64;
    #pragma unroll
    for (int j = 0; j < 2; ++j) {
        const int s  = tid + 256 * j;
        const int sp = s >> 3, e = s & 7;
        frag_t u;
        #pragma unroll
        for (int q = 0; q < 8; ++q)
            u[q] = (short)f2bf(ls[sp][e * 8 + q]);
        *(frag_t*)&xo[sp * 64 + e * 8] = u;
    }
}

// ---- m97-structure conv: B window staged once; A per-step LDS double-buffer ----
__global__ __launch_bounds__(256, 3)
void conv_m97(const unsigned short* __restrict__ xT, const unsigned short* __restrict__ wpA2,
              const float* __restrict__ off, float* __restrict__ out)
{
    __shared__ unsigned short xs[WINR * 64];   // 31 KB, swizzled (r&7)<<3 XOR
    __shared__ unsigned short As[2][4096];     // 2 x 8 KB: [kh][mi][lane][8]

    const int d    = blockIdx.x;
    const int wk   = (d & 7) * (NWG / 8) + (d >> 3);   // bijective XCD swizzle
    const int b    = wk / NT;
    const int sp0  = (wk - b * NT) * BN;
    const int tid  = threadIdx.x;
    const int lane = tid & 63;
    const int wid  = tid >> 6;

    // ---------- prologue: stage B window + A step 0 ----------
    {
        const unsigned short* xb = xT + (size_t)b * SP * 64;
        const int lsw = ((lane & 7) * 8) ^ ((lane >> 3) << 3);
        #pragma unroll
        for (int it = 0; it < 8; ++it) {
            const int R0 = it * 32 + wid * 8;
            const int r  = R0 + (lane >> 3);
            if (r < WINR) {
                int g = sp0 - HALO + r;
                g = min(max(g, 0), SP - 1);
                __builtin_amdgcn_global_load_lds(
                    (const __attribute__((address_space(1))) unsigned int*)
                        (xb + (size_t)g * 64 + lsw),
                    (__attribute__((address_space(3))) unsigned int*)
                        &xs[R0 * 64 + lane * 8],
                    16, 0, 0);
            }
        }
        #pragma unroll
        for (int h = 0; h < 2; ++h)
            __builtin_amdgcn_global_load_lds(
                (const __attribute__((address_space(1))) unsigned int*)
                    (wpA2 + h * KHSTR + tid * 8),
                (__attribute__((address_space(3))) unsigned int*)
                    &As[0][h * 2048 + tid * 8],
                16, 0, 0);
    }
    asm volatile("s_waitcnt vmcnt(0)" ::: "memory");
    __syncthreads();

    const int wm  = (wid >> 1) * 64;   // kout offset (0 / 64)
    const int wn  = (wid & 1) * 64;    // spatial offset (0 / 64)
    const int kh2 = wid >> 1;
    const int l15 = lane & 15;
    const int l4  = lane >> 4;
    const int cread = 8 * l4;

    // ---------- per-(tap, nf) validity masks ----------
    unsigned long long mbits = 0ull;
    int yv[4], xv[4];
    #pragma unroll
    for (int nf = 0; nf < 4; ++nf) {
        const int sp = sp0 + wn + nf * 16 + l15;
        yv[nf] = sp / HWD;
        xv[nf] = sp - yv[nf] * HWD;
    }
    #pragma unroll
    for (int t = 0; t < 9; ++t) {
        const int dy = t / 3 - 1, dx = t % 3 - 1;
        #pragma unroll
        for (int nf = 0; nf < 4; ++nf) {
            const bool v = ((unsigned)(yv[nf] + dy) < (unsigned)HWD) &
                           ((unsigned)(xv[nf] + dx) < (unsigned)HWD);
            mbits |= (unsigned long long)(v ? 1 : 0) << (t * 4 + nf);
        }
    }

    const frag_t zf = {0,0,0,0,0,0,0,0};
    f32x4 acc[4][4] = {};              // [mi][nf]

    // ---------- K loop: 18 steps; A dbuf stage -> LDS reads -> 16 MFMA -> sync ----------
    #pragma unroll
    for (int kc = 0; kc < 18; ++kc) {
        if (kc < 17) {                 // issue next-step A stage (2 loads/thread)
            #pragma unroll
            for (int h = 0; h < 2; ++h)
                __builtin_amdgcn_global_load_lds(
                    (const __attribute__((address_space(1))) unsigned int*)
                        (wpA2 + h * KHSTR + (kc + 1) * 2048 + tid * 8),
                    (__attribute__((address_space(3))) unsigned int*)
                        &As[(kc + 1) & 1][h * 2048 + tid * 8],
                    16, 0, 0);
        }
        const int t  = kc >> 1;
        const int c0 = (kc & 1) * 32;
        const int shift = (t / 3 - 1) * HWD + (t % 3 - 1);
        const int row0  = wn + l15 + HALO + shift;     // in [0, 241]
        const int sw    = (row0 & 7) << 3;
        frag_t a[4], bfr[4];
        #pragma unroll
        for (int mi = 0; mi < 4; ++mi)
            a[mi] = *(const frag_t*)&As[kc & 1][kh2 * 2048 + mi * 512 + lane * 8];
        const unsigned m4 = (unsigned)((mbits >> (t * 4)) & 15ull);
        #pragma unroll
        for (int nf = 0; nf < 4; ++nf) {
            const frag_t bl = *(const frag_t*)&xs[(row0 + 16 * nf) * 64
                                                 + ((c0 + cread) ^ sw)];
            bfr[nf] = ((m4 >> nf) & 1u) ? bl : zf;
        }
        #pragma unroll
        for (int mi = 0; mi < 4; ++mi)
            #pragma unroll
            for (int nf = 0; nf < 4; ++nf)
                acc[mi][nf] = __builtin_amdgcn_mfma_f32_16x16x32_bf16(
                    a[mi], bfr[nf], acc[mi][nf], 0, 0, 0);
        if (kc < 17) {                 // loads had the MFMA cluster to land
            asm volatile("s_waitcnt vmcnt(0)" ::: "memory");
            __syncthreads();
        }
    }

    // ---------- epilogue (tail tile guarded) ----------
    const int spn = sp0 + wn + l15;
    #pragma unroll
    for (int mi = 0; mi < 4; ++mi) {
        const int km = wm + 16 * mi + 4 * l4;
        #pragma unroll
        for (int reg = 0; reg < 4; ++reg) {
            const int  kk  = km + reg;
            const float ofv = off[kk];
            float* ob = out + (size_t)(b * KOUT + kk) * SP;
            #pragma unroll
            for (int nf = 0; nf < 4; ++nf) {
                const int sp = spn + 16 * nf;
                if (sp < SP) ob[sp] = acc[mi][nf][reg] + ofv;
            }
        }
    }
}

// ---- fallback: round-1 fp32 direct conv ----
__global__ __launch_bounds__(256)
void conv3x3_kernel(const float* __restrict__ x, const float* __restrict__ w,
                    const float* __restrict__ off, float* __restrict__ out)
{
    const int s  = blockIdx.x * 256 + threadIdx.x;
    const int b  = s / SP;
    const int sp = s - b * SP;
    const int y  = sp / HWD;
    const int xx = sp - y * HWD;
    const int k0 = blockIdx.y * 4;

    const int   xm1 = (xx > 0) ? xx - 1 : 0;
    const int   xp1 = (xx < HWD - 1) ? xx + 1 : HWD - 1;
    const float m0  = (xx > 0) ? 1.f : 0.f;
    const float m2  = (xx < HWD - 1) ? 1.f : 0.f;

    int ro[3]; float msk[3][3];
    #pragma unroll
    for (int ky = 0; ky < 3; ++ky) {
        const int  yy = y + ky - 1;
        const bool ok = (unsigned)yy < (unsigned)HWD;
        const float rm = ok ? 1.f : 0.f;
        ro[ky] = (ok ? yy : 0) * HWD;
        msk[ky][0] = rm * m0; msk[ky][1] = rm; msk[ky][2] = rm * m2;
    }
    float acc[4] = {0.f, 0.f, 0.f, 0.f};
    const float* xb = x + (size_t)b * CIN * SP;
    for (int c = 0; c < CIN; ++c) {
        const float* xc = xb + (size_t)c * SP;
        #pragma unroll
        for (int ky = 0; ky < 3; ++ky) {
            const float* xr = xc + ro[ky];
            const float v0 = xr[xm1] * msk[ky][0];
            const float v1 = xr[xx]  * msk[ky][1];
            const float v2 = xr[xp1] * msk[ky][2];
            const int wi = c * 9 + ky * 3;
            #pragma unroll
            for (int kk = 0; kk < 4; ++kk) {
                const float* wr = w + (size_t)(k0 + kk) * (CIN * 9) + wi;
                acc[kk] = fmaf(v0, wr[0], acc[kk]);
                acc[kk] = fmaf(v1, wr[1], acc[kk]);
                acc[kk] = fmaf(v2, wr[2], acc[kk]);
            }
        }
    }
    #pragma unroll
    for (int kk = 0; kk < 4; ++kk)
        out[(size_t)(b * KOUT + k0 + kk) * SP + sp] = acc[kk] + off[k0 + kk];
}

} // namespace

extern "C" void kernel_launch(void* const* d_in, const int* in_sizes, int n_in,
                              void* d_out, int out_size, void* d_ws, size_t ws_size,
                              hipStream_t stream)
{
    const float* x   = (const float*)d_in[0];
    const float* w   = (const float*)d_in[1];
    const float* off = (const float*)d_in[2];
    float* out = (float*)d_out;

    const size_t wpa_bytes = (size_t)KOUT * KD * 2;          // 147456
    const size_t xt_bytes  = (size_t)BATCH * SP * CIN * 2;   // 12845056

    if (ws_size >= wpa_bytes + xt_bytes) {
        unsigned short* wpA2 = (unsigned short*)d_ws;
        unsigned short* xT   = (unsigned short*)((char*)d_ws + wpa_bytes);
        prep_kernel<<<TT + WB2, 256, 0, stream>>>(x, w, wpA2, xT);
        conv_m97<<<NWG, dim3(256, 1, 1), 0, stream>>>(xT, wpA2, off, out);
    } else {
        dim3 grid((BATCH * SP) / 256, KOUT / 4);
        conv3x3_kernel<<<grid, dim3(256, 1, 1), 0, stream>>>(x, w, off, out);
    }
}

// Round 13
// 40.759 us; speedup vs baseline: 2.1640x; 1.3232x over previous
//
#include <hip/hip_runtime.h>
#include <hip/hip_bf16.h>

namespace {

using frag_t    = __attribute__((ext_vector_type(8))) short;   // 8 bf16 = 16 B
using f32x4     = __attribute__((ext_vector_type(4))) float;   // MFMA acc
using float4_t  = __attribute__((ext_vector_type(4))) float;

constexpr int BATCH = 32;
constexpr int CIN   = 64;
constexpr int HWD   = 56;
constexpr int KOUT  = 128;
constexpr int SP    = HWD * HWD;        // 3136
constexpr int KD    = 9 * CIN;          // 576
constexpr int BN    = 128;              // spatial tile
constexpr int HALO  = 57;
constexpr int WINR  = BN + 2 * HALO;    // 242 valid staged rows
constexpr int NSTA  = 256;              // allocated rows (32 KB); 248-255 = zeros
constexpr int NT    = SP / BN + 1;      // 25 tiles/image (last half)
constexpr int NWG2  = NT * BATCH * 2;   // 1600 = 8 * 200 (x kh half)
constexpr int TT    = BATCH * (SP / 64);            // 1568 transpose blocks
constexpr int WB2   = (KOUT * KD) / 256;            // 288 weight blocks
constexpr int KHSTR = 18 * 2048;                    // wpA2 kh stride (ushorts)

__device__ inline unsigned short f2bf(float f) {
    __hip_bfloat16 h = __float2bfloat16(f);
    return __builtin_bit_cast(unsigned short, h);
}

// ---- prep: (a) transpose x -> xT[b][sp][c] bf16; (b) repack w lane-ordered ----
// wpA2[kh][kc][mi][lane][8]: lane l: kout = kh*64 + mi*16 + (l&15),
// kk = kc*32 + (l>>4)*8 + q   (R11/R12-verified layout)
__global__ __launch_bounds__(256)
void prep_kernel(const float* __restrict__ x, const float* __restrict__ w,
                 unsigned short* __restrict__ wpA2, unsigned short* __restrict__ xT)
{
    if (blockIdx.x >= TT) {
        const int idx = (blockIdx.x - TT) * 256 + threadIdx.x;   // < 73728
        const int q   = idx & 7;
        int r1 = idx >> 3;
        const int l  = r1 & 63;  r1 >>= 6;
        const int mi = r1 & 3;   r1 >>= 2;
        const int kc = r1 % 18;
        const int kh = r1 / 18;
        const int kout = kh * 64 + mi * 16 + (l & 15);
        const int kk   = kc * 32 + (l >> 4) * 8 + q;
        const int c = kk & 63, t = kk >> 6, ky = t / 3, kx = t - ky * 3;
        wpA2[idx] = f2bf(w[((kout * CIN + c) * 3 + ky) * 3 + kx]);
        return;
    }
    __shared__ float ls[64][68];
    const int bb   = blockIdx.x / (SP / 64);
    const int tile = blockIdx.x - bb * (SP / 64);
    const int sp0  = tile * 64;
    const int tid  = threadIdx.x;
    const int cq   = tid >> 4;
    const int spo  = (tid & 15) * 4;
    const float* xb = x + (size_t)bb * CIN * SP;
    #pragma unroll
    for (int j = 0; j < 4; ++j) {
        const int c = cq + 16 * j;
        float4_t v = *(const float4_t*)&xb[(size_t)c * SP + sp0 + spo];
        ls[spo + 0][c] = v.x; ls[spo + 1][c] = v.y;
        ls[spo + 2][c] = v.z; ls[spo + 3][c] = v.w;
    }
    __syncthreads();
    unsigned short* xo = xT + (size_t)(bb * SP + sp0) * 64;
    #pragma unroll
    for (int j = 0; j < 2; ++j) {
        const int s  = tid + 256 * j;
        const int sp = s >> 3, e = s & 7;
        frag_t u;
        #pragma unroll
        for (int q = 0; q < 8; ++q)
            u[q] = (short)f2bf(ls[sp][e * 8 + q]);
        *(frag_t*)&xo[sp * 64 + e * 8] = u;
    }
}

// ---- A-in-registers implicit-GEMM conv: K-loop is pure LDS + MFMA ----
__global__ __launch_bounds__(256, 4)
void conv_areg(const unsigned short* __restrict__ xT, const unsigned short* __restrict__ wpA2,
               const float* __restrict__ off, float* __restrict__ out)
{
    // xs[row][c] bf16; slot [r][z] holds xT[g(r)][z ^ ((r&7)<<3)]; rows 248-255 = 0
    __shared__ unsigned short xs[NSTA * 64];   // 32 KB

    const int d    = blockIdx.x;
    const int wk   = (d & 7) * (NWG2 / 8) + (d >> 3);  // bijective XCD swizzle
    const int kh   = wk & 1;
    const int wk2  = wk >> 1;
    const int b    = wk2 / NT;
    const int sp0  = (wk2 - b * NT) * BN;
    const int tid  = threadIdx.x;
    const int lane = tid & 63;
    const int wid  = tid >> 6;

    // ---------- stage 242-row window + zero rows 248-255 ----------
    {
        const unsigned short* xb = xT + (size_t)b * SP * 64;
        const int lsw = ((lane & 7) * 8) ^ ((lane >> 3) << 3);
        #pragma unroll
        for (int it = 0; it < 8; ++it) {
            const int R0 = it * 32 + wid * 8;
            const int r  = R0 + (lane >> 3);
            if (r < WINR) {
                int g = sp0 - HALO + r;
                g = min(max(g, 0), SP - 1);
                __builtin_amdgcn_global_load_lds(
                    (const __attribute__((address_space(1))) unsigned int*)
                        (xb + (size_t)g * 64 + lsw),
                    (__attribute__((address_space(3))) unsigned int*)
                        &xs[R0 * 64 + lane * 8],
                    16, 0, 0);
            }
        }
        *(unsigned int*)&xs[248 * 64 + tid * 2] = 0u;   // 512 ushorts of zeros
    }
    asm volatile("s_waitcnt vmcnt(0)" ::: "memory");
    __syncthreads();

    const int l15 = lane & 15;
    const int l4  = lane >> 4;
    const int cread = 8 * l4;
    const int zaddr = 248 * 64 + cread;        // zero-row read address

    // ---------- per-tap validity bitmasks (8 nf bits each) ----------
    unsigned tm[9];
    int yv[8], xv[8];
    #pragma unroll
    for (int nf = 0; nf < 8; ++nf) {
        const int sp = sp0 + nf * 16 + l15;
        yv[nf] = sp / HWD;
        xv[nf] = sp - yv[nf] * HWD;
    }
    #pragma unroll
    for (int t = 0; t < 9; ++t) {
        const int dy = t / 3 - 1, dx = t % 3 - 1;
        unsigned m = 0;
        #pragma unroll
        for (int nf = 0; nf < 8; ++nf) {
            const bool v = ((unsigned)(yv[nf] + dy) < (unsigned)HWD) &
                           ((unsigned)(xv[nf] + dx) < (unsigned)HWD);
            m |= (v ? 1u : 0u) << nf;
        }
        tm[t] = m;
    }

    // wave's A slice base: 16 kouts (kh*64 + wid*16 +), all K
    const unsigned short* ap = wpA2 + (size_t)kh * KHSTR + wid * 512 + lane * 8;

    f32x4 acc[8] = {};                 // [nf]

    // ---------- K loop: 3 passes x 6 kc; A batched into regs per pass ----------
    #pragma unroll
    for (int p = 0; p < 3; ++p) {
        frag_t aA[6];
        #pragma unroll
        for (int j = 0; j < 6; ++j)    // 6 independent global loads, batched
            aA[j] = *(const frag_t*)(ap + (size_t)(p * 6 + j) * 2048);
        #pragma unroll
        for (int j = 0; j < 6; ++j) {
            const int kc = p * 6 + j;
            const int t  = kc >> 1;
            const int c0 = (kc & 1) * 32;
            const int shift = (t / 3 - 1) * HWD + (t % 3 - 1);
            const int row0b = l15 + HALO + shift;      // low 3 bits invariant in nf
            const int sw    = (row0b & 7) << 3;
            const int cadr  = (c0 + cread) ^ sw;
            const unsigned m = tm[t];
            frag_t bfr[8];
            #pragma unroll
            for (int nf = 0; nf < 8; ++nf) {
                const int ba = (row0b + 16 * nf) * 64 + cadr;
                const int ra = ((m >> nf) & 1u) ? ba : zaddr;   // redirect to zero row
                bfr[nf] = *(const frag_t*)&xs[ra];
            }
            #pragma unroll
            for (int nf = 0; nf < 8; ++nf)
                acc[nf] = __builtin_amdgcn_mfma_f32_16x16x32_bf16(
                    aA[j], bfr[nf], acc[nf], 0, 0, 0);
        }
    }

    // ---------- epilogue (tail tile guarded) ----------
    const int km0 = kh * 64 + wid * 16 + 4 * l4;
    const int spn = sp0 + l15;
    #pragma unroll
    for (int reg = 0; reg < 4; ++reg) {
        const int  kk  = km0 + reg;
        const float ofv = off[kk];
        float* ob = out + (size_t)(b * KOUT + kk) * SP;
        #pragma unroll
        for (int nf = 0; nf < 8; ++nf) {
            const int sp = spn + 16 * nf;
            if (sp < SP) ob[sp] = acc[nf][reg] + ofv;
        }
    }
}

// ---- fallback: round-1 fp32 direct conv ----
__global__ __launch_bounds__(256)
void conv3x3_kernel(const float* __restrict__ x, const float* __restrict__ w,
                    const float* __restrict__ off, float* __restrict__ out)
{
    const int s  = blockIdx.x * 256 + threadIdx.x;
    const int b  = s / SP;
    const int sp = s - b * SP;
    const int y  = sp / HWD;
    const int xx = sp - y * HWD;
    const int k0 = blockIdx.y * 4;

    const int   xm1 = (xx > 0) ? xx - 1 : 0;
    const int   xp1 = (xx < HWD - 1) ? xx + 1 : HWD - 1;
    const float m0  = (xx > 0) ? 1.f : 0.f;
    const float m2  = (xx < HWD - 1) ? 1.f : 0.f;

    int ro[3]; float msk[3][3];
    #pragma unroll
    for (int ky = 0; ky < 3; ++ky) {
        const int  yy = y + ky - 1;
        const bool ok = (unsigned)yy < (unsigned)HWD;
        const float rm = ok ? 1.f : 0.f;
        ro[ky] = (ok ? yy : 0) * HWD;
        msk[ky][0] = rm * m0; msk[ky][1] = rm; msk[ky][2] = rm * m2;
    }
    float acc[4] = {0.f, 0.f, 0.f, 0.f};
    const float* xb = x + (size_t)b * CIN * SP;
    for (int c = 0; c < CIN; ++c) {
        const float* xc = xb + (size_t)c * SP;
        #pragma unroll
        for (int ky = 0; ky < 3; ++ky) {
            const float* xr = xc + ro[ky];
            const float v0 = xr[xm1] * msk[ky][0];
            const float v1 = xr[xx]  * msk[ky][1];
            const float v2 = xr[xp1] * msk[ky][2];
            const int wi = c * 9 + ky * 3;
            #pragma unroll
            for (int kk = 0; kk < 4; ++kk) {
                const float* wr = w + (size_t)(k0 + kk) * (CIN * 9) + wi;
                acc[kk] = fmaf(v0, wr[0], acc[kk]);
                acc[kk] = fmaf(v1, wr[1], acc[kk]);
                acc[kk] = fmaf(v2, wr[2], acc[kk]);
            }
        }
    }
    #pragma unroll
    for (int kk = 0; kk < 4; ++kk)
        out[(size_t)(b * KOUT + k0 + kk) * SP + sp] = acc[kk] + off[k0 + kk];
}

} // namespace

extern "C" void kernel_launch(void* const* d_in, const int* in_sizes, int n_in,
                              void* d_out, int out_size, void* d_ws, size_t ws_size,
                              hipStream_t stream)
{
    const float* x   = (const float*)d_in[0];
    const float* w   = (const float*)d_in[1];
    const float* off = (const float*)d_in[2];
    float* out = (float*)d_out;

    const size_t wpa_bytes = (size_t)KOUT * KD * 2;          // 147456
    const size_t xt_bytes  = (size_t)BATCH * SP * CIN * 2;   // 12845056

    if (ws_size >= wpa_bytes + xt_bytes) {
        unsigned short* wpA2 = (unsigned short*)d_ws;
        unsigned short* xT   = (unsigned short*)((char*)d_ws + wpa_bytes);
        prep_kernel<<<TT + WB2, 256, 0, stream>>>(x, w, wpA2, xT);
        conv_areg<<<NWG2, dim3(256, 1, 1), 0, stream>>>(xT, wpA2, off, out);
    } else {
        dim3 grid((BATCH * SP) / 256, KOUT / 4);
        conv3x3_kernel<<<grid, dim3(256, 1, 1), 0, stream>>>(x, w, off, out);
    }
}

// Round 14
// 40.133 us; speedup vs baseline: 2.1977x; 1.0156x over previous
//
#include <hip/hip_runtime.h>
#include <hip/hip_bf16.h>

namespace {

using frag_t    = __attribute__((ext_vector_type(8))) short;   // 8 bf16 = 16 B
using f32x4     = __attribute__((ext_vector_type(4))) float;   // MFMA acc
using float4_t  = __attribute__((ext_vector_type(4))) float;

constexpr int BATCH = 32;
constexpr int CIN   = 64;
constexpr int HWD   = 56;
constexpr int KOUT  = 128;
constexpr int SP    = HWD * HWD;        // 3136 = 49*64
constexpr int KD    = 9 * CIN;          // 576
constexpr int BN    = 64;               // spatial tile (divides SP)
constexpr int HALO  = 57;
constexpr int WINR  = BN + 2 * HALO;    // 178 valid staged rows
constexpr int NSTA  = 192;              // allocated rows (24 KB); 184-191 zeroed
constexpr int NT    = SP / BN;          // 49
constexpr int NWG   = NT * BATCH;       // 1568 = 8 * 196 (full kout per block)
constexpr int TT    = BATCH * (SP / 64);            // 1568 transpose blocks
constexpr int WB2   = (KOUT * KD) / 256;            // 288 weight blocks
constexpr int KHSTR = 18 * 2048;                    // wpA2 kh stride (ushorts)

__device__ inline unsigned short f2bf(float f) {
    __hip_bfloat16 h = __float2bfloat16(f);
    return __builtin_bit_cast(unsigned short, h);
}

// ---- prep: (a) transpose x -> xT[b][sp][c] bf16; (b) repack w lane-ordered ----
// wpA2[kh][kc][mi][lane][8]: lane l: kout = kh*64 + mi*16 + (l&15),
// kk = kc*32 + (l>>4)*8 + q   (verified R11-R13)
__global__ __launch_bounds__(256)
void prep_kernel(const float* __restrict__ x, const float* __restrict__ w,
                 unsigned short* __restrict__ wpA2, unsigned short* __restrict__ xT)
{
    if (blockIdx.x >= TT) {
        const int idx = (blockIdx.x - TT) * 256 + threadIdx.x;   // < 73728
        const int q   = idx & 7;
        int r1 = idx >> 3;
        const int l  = r1 & 63;  r1 >>= 6;
        const int mi = r1 & 3;   r1 >>= 2;
        const int kc = r1 % 18;
        const int kh = r1 / 18;
        const int kout = kh * 64 + mi * 16 + (l & 15);
        const int kk   = kc * 32 + (l >> 4) * 8 + q;
        const int c = kk & 63, t = kk >> 6, ky = t / 3, kx = t - ky * 3;
        wpA2[idx] = f2bf(w[((kout * CIN + c) * 3 + ky) * 3 + kx]);
        return;
    }
    __shared__ float ls[64][68];
    const int bb   = blockIdx.x / (SP / 64);
    const int tile = blockIdx.x - bb * (SP / 64);
    const int sp0  = tile * 64;
    const int tid  = threadIdx.x;
    const int cq   = tid >> 4;
    const int spo  = (tid & 15) * 4;
    const float* xb = x + (size_t)bb * CIN * SP;
    #pragma unroll
    for (int j = 0; j < 4; ++j) {
        const int c = cq + 16 * j;
        float4_t v = *(const float4_t*)&xb[(size_t)c * SP + sp0 + spo];
        ls[spo + 0][c] = v.x; ls[spo + 1][c] = v.y;
        ls[spo + 2][c] = v.z; ls[spo + 3][c] = v.w;
    }
    __syncthreads();
    unsigned short* xo = xT + (size_t)(bb * SP + sp0) * 64;
    #pragma unroll
    for (int j = 0; j < 2; ++j) {
        const int s  = tid + 256 * j;
        const int sp = s >> 3, e = s & 7;
        frag_t u;
        #pragma unroll
        for (int q = 0; q < 8; ++q)
            u[q] = (short)f2bf(ls[sp][e * 8 + q]);
        *(frag_t*)&xo[sp * 64 + e * 8] = u;
    }
}

// ---- conv: full-kout block, mi=2 x nf=4 waves, A reg-batched, no K-loop barriers ----
__global__ __launch_bounds__(256, 4)
void conv_b2(const unsigned short* __restrict__ xT, const unsigned short* __restrict__ wpA2,
             const float* __restrict__ off, float* __restrict__ out)
{
    // xs[row][c] bf16; slot [r][z] holds xT[g(r)][z ^ ((r&7)<<3)]; rows 184-191 = 0
    __shared__ unsigned short xs[NSTA * 64];   // 24 KB

    const int d    = blockIdx.x;
    const int wk   = (d & 7) * (NWG / 8) + (d >> 3);   // bijective XCD swizzle
    const int b    = wk / NT;
    const int sp0  = (wk - b * NT) * BN;
    const int tid  = threadIdx.x;
    const int lane = tid & 63;
    const int wid  = tid >> 6;

    // ---------- stage 178-row window once (shared by all 128 kouts) ----------
    {
        const unsigned short* xb = xT + (size_t)b * SP * 64;
        const int lsw = ((lane & 7) * 8) ^ ((lane >> 3) << 3);
        #pragma unroll
        for (int it = 0; it < 6; ++it) {
            const int R0 = it * 32 + wid * 8;       // wave-uniform base row
            const int r  = R0 + (lane >> 3);
            if (r < WINR) {
                int g = sp0 - HALO + r;
                g = min(max(g, 0), SP - 1);
                __builtin_amdgcn_global_load_lds(
                    (const __attribute__((address_space(1))) unsigned int*)
                        (xb + (size_t)g * 64 + lsw),
                    (__attribute__((address_space(3))) unsigned int*)
                        &xs[R0 * 64 + lane * 8],
                    16, 0, 0);
            }
        }
        *(unsigned int*)&xs[184 * 64 + tid * 2] = 0u;   // rows 184-191 = zeros
    }
    asm volatile("s_waitcnt vmcnt(0)" ::: "memory");
    __syncthreads();

    const int l15 = lane & 15;
    const int l4  = lane >> 4;
    const int cread = 8 * l4;
    const int zaddr = 184 * 64 + cread;        // zero-row read address

    // ---------- per-(tap, nf) validity masks (bit t*4+nf) ----------
    unsigned long long mbits = 0ull;
    int yv[4], xv[4];
    #pragma unroll
    for (int nf = 0; nf < 4; ++nf) {
        const int sp = sp0 + nf * 16 + l15;
        yv[nf] = sp / HWD;
        xv[nf] = sp - yv[nf] * HWD;
    }
    #pragma unroll
    for (int t = 0; t < 9; ++t) {
        const int dy = t / 3 - 1, dx = t % 3 - 1;
        #pragma unroll
        for (int nf = 0; nf < 4; ++nf) {
            const bool v = ((unsigned)(yv[nf] + dy) < (unsigned)HWD) &
                           ((unsigned)(xv[nf] + dx) < (unsigned)HWD);
            mbits |= (unsigned long long)(v ? 1 : 0) << (t * 4 + nf);
        }
    }

    // wave's A base: kouts wid*32 .. wid*32+31  (kh = wid>>1, mi_local = (wid&1)*2+m)
    const unsigned short* ap = wpA2 + (size_t)(wid >> 1) * KHSTR
                                    + (wid & 1) * 1024 + lane * 8;
    const frag_t zf = {0,0,0,0,0,0,0,0};
    f32x4 acc[2][4] = {};              // [m][nf]

    // ---------- K loop: 6 batches x 3 kc; A batched into regs (6 indep loads) ----------
    #pragma unroll
    for (int p = 0; p < 6; ++p) {
        frag_t aB[6];
        #pragma unroll
        for (int j = 0; j < 3; ++j)
            #pragma unroll
            for (int m = 0; m < 2; ++m)
                aB[j * 2 + m] = *(const frag_t*)(ap + (size_t)(p * 3 + j) * 2048 + m * 512);
        #pragma unroll
        for (int j = 0; j < 3; ++j) {
            const int kc = p * 3 + j;
            const int t  = kc >> 1;
            const int c0 = (kc & 1) * 32;
            const int shift = (t / 3 - 1) * HWD + (t % 3 - 1);
            const int row0b = l15 + HALO + shift;      // in [0,129]; low3 nf-invariant
            const int sw    = (row0b & 7) << 3;
            const int cadr  = (c0 + cread) ^ sw;
            const unsigned m4 = (unsigned)((mbits >> (t * 4)) & 15ull);
            frag_t bfr[4];
            #pragma unroll
            for (int nf = 0; nf < 4; ++nf) {
                const int ba = (row0b + 16 * nf) * 64 + cadr;
                const int ra = ((m4 >> nf) & 1u) ? ba : zaddr;   // zero-row redirect
                bfr[nf] = *(const frag_t*)&xs[ra];
            }
            #pragma unroll
            for (int m = 0; m < 2; ++m)
                #pragma unroll
                for (int nf = 0; nf < 4; ++nf)
                    acc[m][nf] = __builtin_amdgcn_mfma_f32_16x16x32_bf16(
                        aB[j * 2 + m], bfr[nf], acc[m][nf], 0, 0, 0);
        }
    }

    // ---------- epilogue (BN divides SP: no guards) ----------
    const int spn = sp0 + l15;
    #pragma unroll
    for (int m = 0; m < 2; ++m) {
        const int km = wid * 32 + m * 16 + 4 * l4;
        #pragma unroll
        for (int reg = 0; reg < 4; ++reg) {
            const int  kk  = km + reg;
            const float ofv = off[kk];
            float* ob = out + (size_t)(b * KOUT + kk) * SP;
            #pragma unroll
            for (int nf = 0; nf < 4; ++nf)
                ob[spn + 16 * nf] = acc[m][nf][reg] + ofv;
        }
    }
}

// ---- fallback: round-1 fp32 direct conv ----
__global__ __launch_bounds__(256)
void conv3x3_kernel(const float* __restrict__ x, const float* __restrict__ w,
                    const float* __restrict__ off, float* __restrict__ out)
{
    const int s  = blockIdx.x * 256 + threadIdx.x;
    const int b  = s / SP;
    const int sp = s - b * SP;
    const int y  = sp / HWD;
    const int xx = sp - y * HWD;
    const int k0 = blockIdx.y * 4;

    const int   xm1 = (xx > 0) ? xx - 1 : 0;
    const int   xp1 = (xx < HWD - 1) ? xx + 1 : HWD - 1;
    const float m0  = (xx > 0) ? 1.f : 0.f;
    const float m2  = (xx < HWD - 1) ? 1.f : 0.f;

    int ro[3]; float msk[3][3];
    #pragma unroll
    for (int ky = 0; ky < 3; ++ky) {
        const int  yy = y + ky - 1;
        const bool ok = (unsigned)yy < (unsigned)HWD;
        const float rm = ok ? 1.f : 0.f;
        ro[ky] = (ok ? yy : 0) * HWD;
        msk[ky][0] = rm * m0; msk[ky][1] = rm; msk[ky][2] = rm * m2;
    }
    float acc[4] = {0.f, 0.f, 0.f, 0.f};
    const float* xb = x + (size_t)b * CIN * SP;
    for (int c = 0; c < CIN; ++c) {
        const float* xc = xb + (size_t)c * SP;
        #pragma unroll
        for (int ky = 0; ky < 3; ++ky) {
            const float* xr = xc + ro[ky];
            const float v0 = xr[xm1] * msk[ky][0];
            const float v1 = xr[xx]  * msk[ky][1];
            const float v2 = xr[xp1] * msk[ky][2];
            const int wi = c * 9 + ky * 3;
            #pragma unroll
            for (int kk = 0; kk < 4; ++kk) {
                const float* wr = w + (size_t)(k0 + kk) * (CIN * 9) + wi;
                acc[kk] = fmaf(v0, wr[0], acc[kk]);
                acc[kk] = fmaf(v1, wr[1], acc[kk]);
                acc[kk] = fmaf(v2, wr[2], acc[kk]);
            }
        }
    }
    #pragma unroll
    for (int kk = 0; kk < 4; ++kk)
        out[(size_t)(b * KOUT + k0 + kk) * SP + sp] = acc[kk] + off[k0 + kk];
}

} // namespace

extern "C" void kernel_launch(void* const* d_in, const int* in_sizes, int n_in,
                              void* d_out, int out_size, void* d_ws, size_t ws_size,
                              hipStream_t stream)
{
    const float* x   = (const float*)d_in[0];
    const float* w   = (const float*)d_in[1];
    const float* off = (const float*)d_in[2];
    float* out = (float*)d_out;

    const size_t wpa_bytes = (size_t)KOUT * KD * 2;          // 147456
    const size_t xt_bytes  = (size_t)BATCH * SP * CIN * 2;   // 12845056

    if (ws_size >= wpa_bytes + xt_bytes) {
        unsigned short* wpA2 = (unsigned short*)d_ws;
        unsigned short* xT   = (unsigned short*)((char*)d_ws + wpa_bytes);
        prep_kernel<<<TT + WB2, 256, 0, stream>>>(x, w, wpA2, xT);
        conv_b2<<<NWG, dim3(256, 1, 1), 0, stream>>>(xT, wpA2, off, out);
    } else {
        dim3 grid((BATCH * SP) / 256, KOUT / 4);
        conv3x3_kernel<<<grid, dim3(256, 1, 1), 0, stream>>>(x, w, off, out);
    }
}